// Round 2
// baseline (199.405 us; speedup 1.0000x reference)
//
#include <hip/hip_runtime.h>
#include <hip/hip_bf16.h>

#define BSAMP 8192
#define NCLS 400
#define DIM 768
#define LOGITS_SIZE (16384LL * 400LL)
#define GEMM_BLOCKS 640   // (16384/128) m-blocks * 5 n-blocks
#define MASK_BLOCKS 16384

typedef __attribute__((ext_vector_type(8))) short short8;
typedef __attribute__((ext_vector_type(4))) float floatx4;

// fp32 -> bf16 round-half-up, two at a time: 2 adds + 1 v_perm
__device__ inline unsigned int packbf(float a, float b) {
    unsigned int ua = __float_as_uint(a) + 0x8000u;
    unsigned int ub = __float_as_uint(b) + 0x8000u;
    // bytes: [ua.b2, ua.b3, ub.b2, ub.b3] -> (bf16(a), bf16(b)) little-endian
    return __builtin_amdgcn_perm(ub, ua, 0x07060302u);
}

__device__ inline uint2 cvt4(float4 f) {
    uint2 r;
    r.x = packbf(f.x, f.y);
    r.y = packbf(f.z, f.w);
    return r;
}

// 2x2 tap from padded m14 (212 floats) with edge clamping via selects.
// base pair loads are at {0,+1,+14,+15} so the compiler can fuse ds_read2_b32.
__device__ inline float bilin_tap(const float* m14, int r0, int c0, float fy, float fx) {
    int base = r0 * 14 + c0;
    float t0 = m14[base];
    float t1 = m14[base + 1];
    float t2 = m14[base + 14];
    float t3 = m14[base + 15];
    bool ce = (c0 < 13), re = (r0 < 13);
    float g00 = t0;
    float g01 = ce ? t1 : t0;
    float g10 = re ? t2 : t0;
    float g11 = re ? (ce ? t3 : t2) : g01;
    return g00 * (1.f - fy) * (1.f - fx) + g01 * (1.f - fy) * fx +
           g10 * fy * (1.f - fx) + g11 * fy * fx;
}

__global__ __launch_bounds__(256, 2) void fused_kernel(const float* __restrict__ attn,
                                                       const int* __restrict__ pos,
                                                       const float* __restrict__ E,
                                                       const float* __restrict__ W,
                                                       const float* __restrict__ bias,
                                                       float* __restrict__ out) {
    __shared__ __align__(16) union {
        struct { unsigned short A[2][128][40]; unsigned short B[2][80][40]; } g;  // 33280 B
        struct { float m14[212]; float cm[196]; float a7[49]; float mv[49]; } m;
    } sm;

    const int bx = blockIdx.x;
    const int t  = threadIdx.x;

    if (bx < GEMM_BLOCKS) {
        // ======================= GEMM: logits = E @ W^T + b =======================
        // tile 128(M) x 80(N), BK=64 (two 32-k slabs), 4 waves, reg-prefetch pipeline
        const int n0 = (bx % 5) * 80;
        const int m0 = (bx / 5) * 128;
        const int wave = t >> 6, lane = t & 63, quad = lane >> 4, l16 = lane & 15;

        // staging: thread t owns col range tCol..tCol+3 of rows tRow+16j
        const int tRow = t >> 4;          // 0..15
        const int tCol = (t & 15) << 2;   // 0..60
        const int slab = tCol >> 5;       // which 32-k slab
        const int kk   = tCol & 31;
        const float* aPtr = E + (size_t)(m0 + tRow) * DIM + tCol;
        const float* bPtr = W + (size_t)(n0 + tRow) * DIM + tCol;
        unsigned short* wA = &sm.g.A[slab][tRow][kk];
        unsigned short* wB = &sm.g.B[slab][tRow][kk];

        float4 pf[13];
#pragma unroll
        for (int j = 0; j < 8; ++j) pf[j] = *(const float4*)(aPtr + j * (16 * DIM));
#pragma unroll
        for (int j = 0; j < 5; ++j) pf[8 + j] = *(const float4*)(bPtr + j * (16 * DIM));

        floatx4 acc[2][5];
#pragma unroll
        for (int mi = 0; mi < 2; ++mi)
#pragma unroll
            for (int ni = 0; ni < 5; ++ni)
                acc[mi][ni] = (floatx4){0.f, 0.f, 0.f, 0.f};

        for (int it = 0; it < 12; ++it) {
            __syncthreads();  // prior iteration's fragment reads complete
#pragma unroll
            for (int j = 0; j < 8; ++j) *(uint2*)(wA + j * (16 * 40)) = cvt4(pf[j]);
#pragma unroll
            for (int j = 0; j < 5; ++j) *(uint2*)(wB + j * (16 * 40)) = cvt4(pf[8 + j]);
            if (it < 11) {  // prefetch next k-slab; completes under the MFMA phase
                const float* aN = aPtr + (it + 1) * 64;
                const float* bN = bPtr + (it + 1) * 64;
#pragma unroll
                for (int j = 0; j < 8; ++j) pf[j] = *(const float4*)(aN + j * (16 * DIM));
#pragma unroll
                for (int j = 0; j < 5; ++j) pf[8 + j] = *(const float4*)(bN + j * (16 * DIM));
            }
            __syncthreads();
#pragma unroll
            for (int s = 0; s < 2; ++s) {
                short8 af0 = *(const short8*)&sm.g.A[s][wave * 32 + l16][quad * 8];
                short8 af1 = *(const short8*)&sm.g.A[s][wave * 32 + 16 + l16][quad * 8];
#pragma unroll
                for (int ni = 0; ni < 5; ++ni) {
                    short8 bfr = *(const short8*)&sm.g.B[s][ni * 16 + l16][quad * 8];
                    acc[0][ni] = __builtin_amdgcn_mfma_f32_16x16x32_bf16(af0, bfr, acc[0][ni], 0, 0, 0);
                    acc[1][ni] = __builtin_amdgcn_mfma_f32_16x16x32_bf16(af1, bfr, acc[1][ni], 0, 0, 0);
                }
            }
        }

        // epilogue: C/D layout col=lane&15, row=quad*4+reg
#pragma unroll
        for (int ni = 0; ni < 5; ++ni) {
            int col = n0 + ni * 16 + l16;
            float bv = bias[col];
#pragma unroll
            for (int mi = 0; mi < 2; ++mi) {
                int rowBase = m0 + wave * 32 + mi * 16 + quad * 4;
#pragma unroll
                for (int r = 0; r < 4; ++r) {
                    out[(size_t)(rowBase + r) * NCLS + col] = acc[mi][ni][r] + bv;
                }
            }
        }
    } else {
        // ======================= mask path: one (sample,box) per block =======================
        const int p = bx - GEMM_BLOCKS;   // 0..16383 = output row
        const int b = p & (BSAMP - 1);
        const int o = p >> 13;
        float* m14 = sm.m.m14;

        if (t < 196) m14[t] = attn[(size_t)b * 196 + t];
        if (t >= 196 && t < 212) m14[t] = 0.f;  // pad (values masked off by selects)

        const int* pb = pos + (size_t)b * 12;
        const float topf  = (float)(pb[o * 4 + 0] - pb[8]);
        const float leftf = (float)(pb[o * 4 + 1] - pb[9]);
        const float oH = (float)pb[o * 4 + 2];
        const float oW = (float)pb[o * 4 + 3];
        const float eH = (float)pb[10];
        const float eW = (float)pb[11];
        __syncthreads();

        const int oy = t / 14;
        const int ox = t - oy * 14;
        if (t < 196) {
            // outer bilinear coords (exact reference op order)
            float ty = fmaxf((oy + 0.5f) * oH / 14.0f - 0.5f, 0.0f);
            float y0 = floorf(ty);
            float y1 = fminf(y0 + 1.0f, oH - 1.0f);
            float wy = ty - y0;
            float tx = fmaxf((ox + 0.5f) * oW / 14.0f - 0.5f, 0.0f);
            float x0 = floorf(tx);
            float x1 = fminf(x0 + 1.0f, oW - 1.0f);
            float wx = tx - x0;
            float Y0 = topf + y0, Y1 = topf + y1;
            float X0 = leftf + x0, X1 = leftf + x1;

            // inner coords, computed once per distinct Y/X (bit-identical expressions)
            float sy0 = fmaxf((Y0 + 0.5f) * 14.0f / eH - 0.5f, 0.0f);
            float r0f = floorf(sy0); int ry0 = (int)r0f; float fy0 = sy0 - r0f;
            float sy1 = fmaxf((Y1 + 0.5f) * 14.0f / eH - 0.5f, 0.0f);
            float r1f = floorf(sy1); int ry1 = (int)r1f; float fy1 = sy1 - r1f;
            float sx0 = fmaxf((X0 + 0.5f) * 14.0f / eW - 0.5f, 0.0f);
            float c0f = floorf(sx0); int cx0 = (int)c0f; float fx0 = sx0 - c0f;
            float sx1 = fmaxf((X1 + 0.5f) * 14.0f / eW - 0.5f, 0.0f);
            float c1f = floorf(sx1); int cx1 = (int)c1f; float fx1 = sx1 - c1f;

            float v00 = bilin_tap(m14, ry0, cx0, fy0, fx0);
            float v01 = bilin_tap(m14, ry0, cx1, fy0, fx1);
            float v10 = bilin_tap(m14, ry1, cx0, fy1, fx0);
            float v11 = bilin_tap(m14, ry1, cx1, fy1, fx1);

            float cmv = v00 * (1.f - wy) * (1.f - wx) + v01 * (1.f - wy) * wx +
                        v10 * wy * (1.f - wx) + v11 * wy * wx;
            sm.m.cm[t] = cmv;
        }
        __syncthreads();

        if (t < 49) {  // 2x2 avg-pool, same accumulation order as before (passed)
            int i7 = t / 7, j7 = t - i7 * 7;
            const float* c = sm.m.cm;
            int b0 = (2 * i7) * 14 + 2 * j7;
            float s = ((c[b0] + c[b0 + 1]) + c[b0 + 14]) + c[b0 + 15];
            sm.m.a7[t] = s * 0.25f;
        }
        __syncthreads();

        if (t < 49) {  // rank: stable top-25 (jax.lax.top_k tie-break to lower index)
            float mine = sm.m.a7[t];
            int cnt = 0;
#pragma unroll 7
            for (int s2 = 0; s2 < 49; ++s2) {
                float v = sm.m.a7[s2];
                cnt += (v > mine) || (v == mine && s2 < t);
            }
            sm.m.mv[t] = (cnt < 25) ? 0.0f : 1.0f;
        }
        __syncthreads();

        if (t < 196) {
            out[LOGITS_SIZE + (size_t)p * 196 + t] = sm.m.mv[(oy >> 1) * 7 + (ox >> 1)];
        }
    }
}

extern "C" void kernel_launch(void* const* d_in, const int* in_sizes, int n_in,
                              void* d_out, int out_size, void* d_ws, size_t ws_size,
                              hipStream_t stream) {
    const float* attn = (const float*)d_in[0];
    const int*   pos  = (const int*)d_in[1];
    const float* E    = (const float*)d_in[2];
    const float* W    = (const float*)d_in[3];
    const float* bias = (const float*)d_in[4];
    float* out = (float*)d_out;

    fused_kernel<<<GEMM_BLOCKS + MASK_BLOCKS, 256, 0, stream>>>(attn, pos, E, W, bias, out);
}

// Round 3
// 169.511 us; speedup vs baseline: 1.1764x; 1.1764x over previous
//
#include <hip/hip_runtime.h>
#include <hip/hip_bf16.h>

#define BSAMP 8192
#define NCLS 400
#define DIM 768
#define LOGITS_SIZE (16384LL * 400LL)
#define GEMM_BLOCKS 640     // 128 m-blocks x 5 n-blocks
#define MASK_BLOCKS 4096    // 4 (sample,box) pairs per 256-thr block
#define W_ELEMS (NCLS * DIM)

typedef __attribute__((ext_vector_type(8))) short short8;
typedef __attribute__((ext_vector_type(4))) float floatx4;

// fp32 -> bf16 round-half-up, two at a time: 2 adds + 1 v_perm
__device__ inline unsigned int packbf(float a, float b) {
    unsigned int ua = __float_as_uint(a) + 0x8000u;
    unsigned int ub = __float_as_uint(b) + 0x8000u;
    return __builtin_amdgcn_perm(ub, ua, 0x07060302u);  // [ua.b2,ua.b3,ub.b2,ub.b3]
}

__device__ inline short8 cvt8(float4 lo, float4 hi) {
    union { unsigned int u[4]; short8 s; } r;
    r.u[0] = packbf(lo.x, lo.y);
    r.u[1] = packbf(lo.z, lo.w);
    r.u[2] = packbf(hi.x, hi.y);
    r.u[3] = packbf(hi.z, hi.w);
    return r.s;
}

// W fp32 -> bf16 pre-convert (0.6 MB into d_ws); runs every launch (ws re-poisoned)
__global__ void cvtW_kernel(const float* __restrict__ W, unsigned short* __restrict__ ws) {
    int i = (blockIdx.x * 256 + threadIdx.x) * 4;
    if (i < W_ELEMS) {
        float4 f = *(const float4*)(W + i);
        uint2 r;
        r.x = packbf(f.x, f.y);
        r.y = packbf(f.z, f.w);
        *(uint2*)(ws + i) = r;
    }
}

__device__ inline float bilin14(const float* m14, float Y, float X, float eH, float eW) {
    float sy = fmaxf((Y + 0.5f) * 14.0f / eH - 0.5f, 0.0f);
    float sx = fmaxf((X + 0.5f) * 14.0f / eW - 0.5f, 0.0f);
    float r0f = floorf(sy);
    float c0f = floorf(sx);
    int r0 = (int)r0f;
    int r1 = min(r0 + 1, 13);
    int c0 = (int)c0f;
    int c1 = min(c0 + 1, 13);
    float fy = sy - r0f;
    float fx = sx - c0f;
    float g00 = m14[r0 * 14 + c0];
    float g01 = m14[r0 * 14 + c1];
    float g10 = m14[r1 * 14 + c0];
    float g11 = m14[r1 * 14 + c1];
    return g00 * (1.f - fy) * (1.f - fx) + g01 * (1.f - fy) * fx +
           g10 * fy * (1.f - fx) + g11 * fy * fx;
}

// One kernel, two block roles. GEMM blocks: NO LDS, NO barriers — direct-from-global
// MFMA fragments, fully unrolled K with register double-buffer. Mask blocks: 4 waves,
// one (sample,box) pair per wave (R1's verified math, bit-identical op order).
template <bool USE_WS>
__global__ __launch_bounds__(256, 4) void fused_kernel(const float* __restrict__ attn,
                                                       const int* __restrict__ pos,
                                                       const float* __restrict__ E,
                                                       const float* __restrict__ W,
                                                       const float* __restrict__ bias,
                                                       const unsigned short* __restrict__ wsW,
                                                       float* __restrict__ out) {
    __shared__ float m14s[4][196];
    __shared__ float a7s[4][49];
    __shared__ float mvs[4][49];

    const int bx = blockIdx.x;
    const int t  = threadIdx.x;

    if (bx < GEMM_BLOCKS) {
        // ---- swizzle: 5 n-blocks of one m-octet dispatch adjacently (A L2/L3 reuse) ----
        const int g  = bx >> 3, xo = bx & 7;
        const int n0 = (g % 5) * 80;
        const int m0 = (((g / 5) << 3) + xo) << 7;   // *128
        const int wave = t >> 6, lane = t & 63, quad = lane >> 4, l16 = lane & 15;

        // A: wave owns rows [m0+32w, +32); frag mi covers rows +16*mi; lane reads 8 fp32 at k+quad*8
        const float* aBase = E + (size_t)(m0 + wave * 32 + l16) * DIM + quad * 8;
        const size_t bOff = (size_t)(n0 + l16) * DIM + quad * 8;  // + ni*16*DIM + k

        floatx4 acc[2][5];
#pragma unroll
        for (int mi = 0; mi < 2; ++mi)
#pragma unroll
            for (int ni = 0; ni < 5; ++ni)
                acc[mi][ni] = (floatx4){0.f, 0.f, 0.f, 0.f};

        float4 A0[2], A1[2];
        short8 BP[5];
        float4 B0[5], B1[5];

#pragma unroll
        for (int mi = 0; mi < 2; ++mi) {
            A0[mi] = *(const float4*)(aBase + mi * 16 * DIM);
            A1[mi] = *(const float4*)(aBase + mi * 16 * DIM + 4);
        }
#pragma unroll
        for (int ni = 0; ni < 5; ++ni) {
            if (USE_WS) {
                BP[ni] = *(const short8*)(wsW + bOff + (size_t)ni * 16 * DIM);
            } else {
                B0[ni] = *(const float4*)(W + bOff + (size_t)ni * 16 * DIM);
                B1[ni] = *(const float4*)(W + bOff + (size_t)ni * 16 * DIM + 4);
            }
        }

#pragma unroll
        for (int it = 0; it < 24; ++it) {
            float4 nA0[2], nA1[2];
            short8 nBP[5];
            float4 nB0[5], nB1[5];
            if (it < 23) {
                const int kn = (it + 1) * 32;
#pragma unroll
                for (int mi = 0; mi < 2; ++mi) {
                    nA0[mi] = *(const float4*)(aBase + mi * 16 * DIM + kn);
                    nA1[mi] = *(const float4*)(aBase + mi * 16 * DIM + kn + 4);
                }
#pragma unroll
                for (int ni = 0; ni < 5; ++ni) {
                    if (USE_WS) {
                        nBP[ni] = *(const short8*)(wsW + bOff + (size_t)ni * 16 * DIM + kn);
                    } else {
                        nB0[ni] = *(const float4*)(W + bOff + (size_t)ni * 16 * DIM + kn);
                        nB1[ni] = *(const float4*)(W + bOff + (size_t)ni * 16 * DIM + kn + 4);
                    }
                }
            }

            short8 af0 = cvt8(A0[0], A1[0]);
            short8 af1 = cvt8(A0[1], A1[1]);
#pragma unroll
            for (int ni = 0; ni < 5; ++ni) {
                short8 bfr = USE_WS ? BP[ni] : cvt8(B0[ni], B1[ni]);
                acc[0][ni] = __builtin_amdgcn_mfma_f32_16x16x32_bf16(af0, bfr, acc[0][ni], 0, 0, 0);
                acc[1][ni] = __builtin_amdgcn_mfma_f32_16x16x32_bf16(af1, bfr, acc[1][ni], 0, 0, 0);
            }

            if (it < 23) {
#pragma unroll
                for (int mi = 0; mi < 2; ++mi) { A0[mi] = nA0[mi]; A1[mi] = nA1[mi]; }
#pragma unroll
                for (int ni = 0; ni < 5; ++ni) {
                    if (USE_WS) BP[ni] = nBP[ni];
                    else { B0[ni] = nB0[ni]; B1[ni] = nB1[ni]; }
                }
            }
        }

        // ---- epilogue: C/D layout col=lane&15, row=quad*4+reg ----
#pragma unroll
        for (int ni = 0; ni < 5; ++ni) {
            int col = n0 + ni * 16 + l16;
            float bv = bias[col];
#pragma unroll
            for (int mi = 0; mi < 2; ++mi) {
                int rowBase = m0 + wave * 32 + mi * 16 + quad * 4;
#pragma unroll
                for (int r = 0; r < 4; ++r) {
                    out[(size_t)(rowBase + r) * NCLS + col] = acc[mi][ni][r] + bv;
                }
            }
        }
    } else {
        // ======================= mask path: 4 pairs per block, 1 per wave =======================
        const int wv = t >> 6, ln = t & 63;
        const int p = (bx - GEMM_BLOCKS) * 4 + wv;   // 0..16383 output row
        const int b = p & (BSAMP - 1);
        const int o = p >> 13;
        float* m14 = m14s[wv];

        for (int i = ln; i < 196; i += 64) m14[i] = attn[(size_t)b * 196 + i];

        const int* pb = pos + (size_t)b * 12;
        const float topf  = (float)(pb[o * 4 + 0] - pb[8]);
        const float leftf = (float)(pb[o * 4 + 1] - pb[9]);
        const float oH = (float)pb[o * 4 + 2];
        const float oW = (float)pb[o * 4 + 3];
        const float eH = (float)pb[10];
        const float eW = (float)pb[11];
        __syncthreads();

        const int i7 = ln / 7, j7 = ln - i7 * 7;
        if (ln < 49) {
            float s = 0.f;
#pragma unroll
            for (int dy = 0; dy < 2; ++dy) {
                int oy = 2 * i7 + dy;
                float ty = fmaxf((oy + 0.5f) * oH / 14.0f - 0.5f, 0.0f);
                float y0 = floorf(ty);
                float y1 = fminf(y0 + 1.0f, oH - 1.0f);
                float wy = ty - y0;
                float Y0 = topf + y0, Y1 = topf + y1;
#pragma unroll
                for (int dx = 0; dx < 2; ++dx) {
                    int ox = 2 * j7 + dx;
                    float tx = fmaxf((ox + 0.5f) * oW / 14.0f - 0.5f, 0.0f);
                    float x0 = floorf(tx);
                    float x1 = fminf(x0 + 1.0f, oW - 1.0f);
                    float wx = tx - x0;
                    float X0 = leftf + x0, X1 = leftf + x1;
                    float v00 = bilin14(m14, Y0, X0, eH, eW);
                    float v01 = bilin14(m14, Y0, X1, eH, eW);
                    float v10 = bilin14(m14, Y1, X0, eH, eW);
                    float v11 = bilin14(m14, Y1, X1, eH, eW);
                    float cm = v00 * (1.f - wy) * (1.f - wx) + v01 * (1.f - wy) * wx +
                               v10 * wy * (1.f - wx) + v11 * wy * wx;
                    s += cm;
                }
            }
            a7s[wv][ln] = s * 0.25f;
        }
        __syncthreads();

        if (ln < 49) {  // stable top-25 rank (jax.lax.top_k tie-break to lower index)
            float mine = a7s[wv][ln];
            int cnt = 0;
#pragma unroll 7
            for (int s2 = 0; s2 < 49; ++s2) {
                float v = a7s[wv][s2];
                cnt += (v > mine) || (v == mine && s2 < ln);
            }
            mvs[wv][ln] = (cnt < 25) ? 0.0f : 1.0f;
        }
        __syncthreads();

        float* ob = out + LOGITS_SIZE + (size_t)p * 196;
        for (int i = ln; i < 196; i += 64) {
            int oy = i / 14, ox = i - oy * 14;
            ob[i] = mvs[wv][(oy >> 1) * 7 + (ox >> 1)];
        }
    }
}

extern "C" void kernel_launch(void* const* d_in, const int* in_sizes, int n_in,
                              void* d_out, int out_size, void* d_ws, size_t ws_size,
                              hipStream_t stream) {
    const float* attn = (const float*)d_in[0];
    const int*   pos  = (const int*)d_in[1];
    const float* E    = (const float*)d_in[2];
    const float* W    = (const float*)d_in[3];
    const float* bias = (const float*)d_in[4];
    float* out = (float*)d_out;

    if (ws_size >= (size_t)W_ELEMS * 2) {
        unsigned short* ws = (unsigned short*)d_ws;
        cvtW_kernel<<<300, 256, 0, stream>>>(W, ws);
        fused_kernel<true><<<GEMM_BLOCKS + MASK_BLOCKS, 256, 0, stream>>>(
            attn, pos, E, W, bias, ws, out);
    } else {
        fused_kernel<false><<<GEMM_BLOCKS + MASK_BLOCKS, 256, 0, stream>>>(
            attn, pos, E, W, bias, nullptr, out);
    }
}